// Round 10
// baseline (151.874 us; speedup 1.0000x reference)
//
#include <hip/hip_runtime.h>
#include <math.h>

#define NB 32     // batch
#define NC 256    // channels
#define NT 512    // time
#define NH 8      // heads
#define ND 32     // head dim
#define SCALE 0.17677669529663687f            // 1/sqrt(32)
#define LOG2E 1.4426950408889634f
#define QSCALE (SCALE * LOG2E)                // folded into Wq/bq (relu commutes with +scale)
#define DEFER_THR 8.0f                        // defer-max threshold (base-2)

typedef __attribute__((ext_vector_type(8))) __bf16 bf16x8;
typedef __attribute__((ext_vector_type(4))) __bf16 bf16x4;
typedef __attribute__((ext_vector_type(4))) float  f32x4;

static __device__ __forceinline__ f32x4 mfma16x16x32(bf16x8 a, bf16x8 b, f32x4 c) {
    return __builtin_amdgcn_mfma_f32_16x16x32_bf16(a, b, c, 0, 0, 0);
}

// =====================================================================
// Prep 1: seq f32 [b,c,t] -> seqT bf16 [b,t,c] (LDS transpose, once).
// =====================================================================
__global__ __launch_bounds__(256) void prep_seq(
    const float* __restrict__ seq, __bf16* __restrict__ seqT)
{
    __shared__ __bf16 lds[64][264];
    const int tid = threadIdx.x;
    const int t0  = blockIdx.x * 64;
    const int bb  = blockIdx.y;
    #pragma unroll
    for (int it = 0; it < 16; ++it) {
        const int lin = it*256 + tid;
        const int c = lin >> 4, t4 = (lin & 15) * 4;
        const float4 v = *(const float4*)&seq[((size_t)(bb*NC + c))*NT + t0 + t4];
        lds[t4+0][c] = (__bf16)v.x;
        lds[t4+1][c] = (__bf16)v.y;
        lds[t4+2][c] = (__bf16)v.z;
        lds[t4+3][c] = (__bf16)v.w;
    }
    __syncthreads();
    #pragma unroll
    for (int it = 0; it < 8; ++it) {
        const int lin = it*256 + tid;
        const int row = lin >> 5, u = lin & 31;
        *(uint4*)&seqT[((size_t)(bb*NT) + t0 + row)*NC + u*8] = *(const uint4*)&lds[row][u*8];
    }
}

// =====================================================================
// Prep 2: W f32 -> bf16 [p][co][c], QSCALE folded into Wq; zero BN stats.
// =====================================================================
__global__ __launch_bounds__(256) void prep_w(
    const float* __restrict__ Wq, const float* __restrict__ Wk,
    const float* __restrict__ Wv, __bf16* __restrict__ Wb,
    float* __restrict__ stats)
{
    const int tid = threadIdx.x;
    if (blockIdx.x == 0 && tid < 128)
        ((float4*)stats)[tid] = make_float4(0.f, 0.f, 0.f, 0.f);
    const int lin = blockIdx.x*256 + tid;       // float4 units, 49152 total
    const int p = lin >> 14;
    const int r = lin & 16383;
    const float* W = (p == 0) ? Wq : ((p == 1) ? Wk : Wv);
    const float sc = (p == 0) ? QSCALE : 1.f;
    const float4 v = *(const float4*)&W[(size_t)r*4];
    bf16x4 o;
    o[0] = (__bf16)(v.x*sc); o[1] = (__bf16)(v.y*sc);
    o[2] = (__bf16)(v.z*sc); o[3] = (__bf16)(v.w*sc);
    *(bf16x4*)&Wb[(size_t)p*65536 + (size_t)r*4] = o;
}

// =====================================================================
// Kernel 1: QKV projection, bf16 MFMA. Block = 128t x 64co, 256 thr =
// 4 waves; wave owns 32 t (2 ct-subtiles). A-fragments DIRECT from
// global seqT (1 load -> 24 mfma, next-chunk prefetch). W staged via
// uint4 copies into double-buffered LDS; 1 barrier per K-chunk.
// Q,K out [b,h,t,j]; V out [b,h,j,t] with masked key rows zeroed.
// =====================================================================
__global__ __launch_bounds__(256) void qkv_mfma(
    const __bf16* __restrict__ seqT, const __bf16* __restrict__ Wb,
    const float* __restrict__ bq, const float* __restrict__ bk,
    const float* __restrict__ bv, const int* __restrict__ mask,
    __bf16* __restrict__ Qh, __bf16* __restrict__ Kh, __bf16* __restrict__ VhT)
{
    __shared__ __bf16 Ws[2][3][64][40];   // [buf][p][co][c-chunk]

    const int tid = threadIdx.x;
    const int t0  = blockIdx.x * 128;
    const int co0 = blockIdx.y * 64;
    const int bb  = blockIdx.z;
    const int l = tid & 63, w = tid >> 6, lr = l & 15, g = l >> 4;

    const int s_co = tid >> 2, s_c8 = (tid & 3) * 8;   // W staging map
    const __bf16* sp = seqT + ((size_t)(bb*NT) + t0 + w*32)*NC;   // wave's A base

    f32x4 acc[3][4][2];
    #pragma unroll
    for (int p = 0; p < 3; ++p)
        #pragma unroll
        for (int n = 0; n < 4; ++n)
            #pragma unroll
            for (int ct = 0; ct < 2; ++ct) acc[p][n][ct] = (f32x4)0.f;

    // prologue: stage chunk 0, prefetch chunk-1 W regs, load chunk-0 A frags
    uint4 wreg[3];
    #pragma unroll
    for (int p = 0; p < 3; ++p)
        wreg[p] = *(const uint4*)&Wb[((size_t)p*256 + co0 + s_co)*NC + s_c8];
    #pragma unroll
    for (int p = 0; p < 3; ++p)
        *(uint4*)&Ws[0][p][s_co][s_c8] = wreg[p];
    #pragma unroll
    for (int p = 0; p < 3; ++p)
        wreg[p] = *(const uint4*)&Wb[((size_t)p*256 + co0 + s_co)*NC + 32 + s_c8];

    bf16x8 a[2];
    #pragma unroll
    for (int ct = 0; ct < 2; ++ct)
        a[ct] = *(const bf16x8*)&sp[(ct*16 + lr)*NC + g*8];

    for (int kc = 0; kc < 8; ++kc) {
        __syncthreads();   // buf kc&1 staged by all; prior mfma done with buf^1
        if (kc < 7) {
            #pragma unroll
            for (int p = 0; p < 3; ++p)
                *(uint4*)&Ws[(kc+1)&1][p][s_co][s_c8] = wreg[p];
        }
        if (kc < 6) {
            #pragma unroll
            for (int p = 0; p < 3; ++p)
                wreg[p] = *(const uint4*)&Wb[((size_t)p*256 + co0 + s_co)*NC + (kc+2)*32 + s_c8];
        }
        // prefetch next A fragments
        bf16x8 a_nxt[2];
        const int kn = (kc < 7) ? kc + 1 : 7;
        #pragma unroll
        for (int ct = 0; ct < 2; ++ct)
            a_nxt[ct] = *(const bf16x8*)&sp[(ct*16 + lr)*NC + kn*32 + g*8];

        __builtin_amdgcn_s_setprio(1);
        #pragma unroll
        for (int p = 0; p < 3; ++p) {
            bf16x8 wf[4];
            #pragma unroll
            for (int n = 0; n < 4; ++n)
                wf[n] = *(const bf16x8*)&Ws[kc&1][p][n*16 + lr][g*8];
            #pragma unroll
            for (int n = 0; n < 4; ++n)
                #pragma unroll
                for (int ct = 0; ct < 2; ++ct)
                    acc[p][n][ct] = mfma16x16x32(a[ct], wf[n], acc[p][n][ct]);
        }
        __builtin_amdgcn_s_setprio(0);
        a[0] = a_nxt[0]; a[1] = a_nxt[1];
    }

    // ---- epilogue ----
    #pragma unroll
    for (int ct = 0; ct < 2; ++ct) {
        const int tb = t0 + w*32 + ct*16 + g*4;   // + r
        // Q, K: bias + relu, scalar bf16 stores [b,h,t,j]
        #pragma unroll
        for (int p = 0; p < 2; ++p) {
            #pragma unroll
            for (int n = 0; n < 4; ++n) {
                const int c  = co0 + n*16 + lr;
                const int hh = c >> 5, jj = c & 31;
                const float bv_ = (p == 0) ? bq[c]*QSCALE : bk[c];
                __bf16* op = (p == 0 ? Qh : Kh) + ((size_t)(bb*NH + hh)*NT)*ND + jj;
                #pragma unroll
                for (int r = 0; r < 4; ++r)
                    op[(size_t)(tb + r)*ND] = (__bf16)fmaxf(acc[p][n][ct][r] + bv_, 0.f);
            }
        }
        // V: bias + relu + key-mask zero, vectorized store [b,h,j,t]
        float km[4];
        #pragma unroll
        for (int r = 0; r < 4; ++r)
            km[r] = (mask[bb*NT + tb + r] != 0) ? 1.f : 0.f;
        #pragma unroll
        for (int n = 0; n < 4; ++n) {
            const int c  = co0 + n*16 + lr;
            const int hh = c >> 5, jj = c & 31;
            const float bv_ = bv[c];
            bf16x4 vv;
            #pragma unroll
            for (int r = 0; r < 4; ++r)
                vv[r] = (__bf16)(fmaxf(acc[2][n][ct][r] + bv_, 0.f) * km[r]);
            *(bf16x4*)&VhT[((size_t)(bb*NH + hh)*ND + jj)*NT + tb] = vv;
        }
    }
}

// =====================================================================
// Kernel 2: flash attention (unchanged from round 7 — measured win).
// 4 waves; wave owns 32 q-rows. K in LDS; V^T + mask row in swizzled
// LDS; raw-max in-register softmax; l via mask-column MFMA; defer-max.
// =====================================================================
__global__ __launch_bounds__(256) void attn_mfma(
    const __bf16* __restrict__ Qh, const __bf16* __restrict__ Kh,
    const __bf16* __restrict__ VhT, const int* __restrict__ mask,
    float* __restrict__ xout, float* __restrict__ stats)
{
    __shared__ __bf16 Ks[64][40];
    __shared__ __bf16 VTs[33*64];
    __shared__ __bf16 PA[128*64];
    __shared__ float  bnsum[32][4];
    __shared__ float  bnsum2[32][4];

    const int tid = threadIdx.x;
    const int t0  = blockIdx.x * 128;
    const int h   = blockIdx.y;
    const int bb  = blockIdx.z;
    const int bh  = bb*NH + h;
    const __bf16* Qp = Qh  + (size_t)bh*NT*ND;
    const __bf16* Kp = Kh  + (size_t)bh*NT*ND;
    const __bf16* Vp = VhT + (size_t)bh*ND*NT;

    const int l   = tid & 63;
    const int w   = tid >> 6;
    const int lr  = l & 15;
    const int g   = l >> 4;
    const int swz = (lr & 7) << 3;

    bf16x8 qb[2];
    #pragma unroll
    for (int ct = 0; ct < 2; ++ct)
        qb[ct] = *(const bf16x8*)&Qp[(size_t)(t0 + w*32 + ct*16 + lr)*ND + g*8];

    f32x4 accO[2][2];
    f32x4 accL[2];
    #pragma unroll
    for (int jt = 0; jt < 2; ++jt)
        #pragma unroll
        for (int ct = 0; ct < 2; ++ct) accO[jt][ct] = (f32x4)0.f;
    accL[0] = (f32x4)0.f; accL[1] = (f32x4)0.f;
    float m_run[2] = {-1e30f, -1e30f};

    const int kv_s = tid >> 2, kv_c8 = (tid & 3) * 8;
    const int vt_j = tid >> 3, vt_s8 = (tid & 7) * 8;

    uint4 kreg = *(const uint4*)&Kp[(size_t)kv_s*ND + kv_c8];
    uint4 vreg = *(const uint4*)&Vp[(size_t)vt_j*NT + vt_s8];
    int   mreg = (tid < 64) ? mask[bb*NT + tid] : 0;

    for (int s0 = 0; s0 < NT; s0 += 64) {
        __syncthreads();
        *(uint4*)&Ks[kv_s][kv_c8] = kreg;
        *(uint4*)&VTs[vt_j*64 + (vt_s8 ^ ((vt_j & 7) << 3))] = vreg;
        if (tid < 64) VTs[32*64 + tid] = (__bf16)(mreg ? 1.f : 0.f);
        __syncthreads();

        if (s0 + 64 < NT) {
            const int sn = s0 + 64;
            kreg = *(const uint4*)&Kp[(size_t)(sn + kv_s)*ND + kv_c8];
            vreg = *(const uint4*)&Vp[(size_t)vt_j*NT + sn + vt_s8];
            if (tid < 64) mreg = mask[bb*NT + sn + tid];
        }

        bf16x8 kA[4];
        #pragma unroll
        for (int st = 0; st < 4; ++st)
            kA[st] = *(const bf16x8*)&Ks[st*16 + lr][g*8];
        f32x4 sst[2][4];
        __builtin_amdgcn_s_setprio(1);
        #pragma unroll
        for (int ct = 0; ct < 2; ++ct)
            #pragma unroll
            for (int st = 0; st < 4; ++st)
                sst[ct][st] = mfma16x16x32(kA[st], qb[ct], (f32x4)0.f);
        __builtin_amdgcn_s_setprio(0);

        #pragma unroll
        for (int ct = 0; ct < 2; ++ct) {
            float mx = -1e30f;
            #pragma unroll
            for (int st = 0; st < 4; ++st)
                #pragma unroll
                for (int r = 0; r < 4; ++r) mx = fmaxf(mx, sst[ct][st][r]);
            mx = fmaxf(mx, __shfl_xor(mx, 16));
            mx = fmaxf(mx, __shfl_xor(mx, 32));

            if (!__all(mx <= m_run[ct] + DEFER_THR)) {
                const float m_new = fmaxf(m_run[ct], mx);
                const float f = exp2f(m_run[ct] - m_new);
                #pragma unroll
                for (int jt = 0; jt < 2; ++jt)
                    #pragma unroll
                    for (int r = 0; r < 4; ++r) accO[jt][ct][r] *= f;
                #pragma unroll
                for (int r = 0; r < 4; ++r) accL[ct][r] *= f;
                m_run[ct] = m_new;
            }

            const int trow = w*32 + ct*16 + lr;
            #pragma unroll
            for (int st = 0; st < 4; ++st) {
                bf16x4 pb4;
                #pragma unroll
                for (int r = 0; r < 4; ++r)
                    pb4[r] = (__bf16)exp2f(sst[ct][st][r] - m_run[ct]);
                *(bf16x4*)&PA[trow*64 + ((st*16 + g*4) ^ swz)] = pb4;
            }
        }

        __builtin_amdgcn_s_setprio(1);
        #pragma unroll
        for (int kh = 0; kh < 2; ++kh) {
            const int co = (kh*32 + g*8);
            bf16x8 va[2], pb[2];
            #pragma unroll
            for (int jt = 0; jt < 2; ++jt)
                va[jt] = *(const bf16x8*)&VTs[(jt*16 + lr)*64 + (co ^ swz)];
            const bf16x8 vam = *(const bf16x8*)&VTs[32*64 + co];
            #pragma unroll
            for (int ct = 0; ct < 2; ++ct)
                pb[ct] = *(const bf16x8*)&PA[(w*32 + ct*16 + lr)*64 + (co ^ swz)];
            #pragma unroll
            for (int jt = 0; jt < 2; ++jt)
                #pragma unroll
                for (int ct = 0; ct < 2; ++ct)
                    accO[jt][ct] = mfma16x16x32(va[jt], pb[ct], accO[jt][ct]);
            #pragma unroll
            for (int ct = 0; ct < 2; ++ct)
                accL[ct] = mfma16x16x32(vam, pb[ct], accL[ct]);
        }
        __builtin_amdgcn_s_setprio(0);
    }

    float psum[2][4], psq[2][4];
    #pragma unroll
    for (int jt = 0; jt < 2; ++jt)
        #pragma unroll
        for (int r = 0; r < 4; ++r) { psum[jt][r] = 0.f; psq[jt][r] = 0.f; }

    #pragma unroll
    for (int ct = 0; ct < 2; ++ct) {
        const int t = t0 + w*32 + ct*16 + lr;
        const float rl = mask[bb*NT + t] ? (1.f / accL[ct][0]) : 0.f;
        #pragma unroll
        for (int jt = 0; jt < 2; ++jt) {
            #pragma unroll
            for (int r = 0; r < 4; ++r) {
                const int c = h*ND + jt*16 + g*4 + r;
                const float o = accO[jt][ct][r] * rl;
                xout[((size_t)(bb*NC + c))*NT + t] = o;
                psum[jt][r] += o;
                psq[jt][r]  += o*o;
            }
        }
    }
    #pragma unroll
    for (int jt = 0; jt < 2; ++jt)
        #pragma unroll
        for (int r = 0; r < 4; ++r)
            #pragma unroll
            for (int off = 1; off < 16; off <<= 1) {
                psum[jt][r] += __shfl_xor(psum[jt][r], off);
                psq[jt][r]  += __shfl_xor(psq[jt][r],  off);
            }
    if (lr == 0) {
        #pragma unroll
        for (int jt = 0; jt < 2; ++jt)
            #pragma unroll
            for (int r = 0; r < 4; ++r) {
                bnsum [jt*16 + g*4 + r][w] = psum[jt][r];
                bnsum2[jt*16 + g*4 + r][w] = psq[jt][r];
            }
    }
    __syncthreads();
    if (tid < 32) {
        const float s  = bnsum [tid][0] + bnsum [tid][1] + bnsum [tid][2] + bnsum [tid][3];
        const float s2 = bnsum2[tid][0] + bnsum2[tid][1] + bnsum2[tid][2] + bnsum2[tid][3];
        atomicAdd(&stats[h*ND + tid], s);
        atomicAdd(&stats[NC + h*ND + tid], s2);
    }
}

// =====================================================================
// Kernel 3: BN normalize + affine + re-mask, in place on d_out.
// =====================================================================
__global__ __launch_bounds__(256) void bn_apply_kernel(
    float* __restrict__ x, const float* __restrict__ stats,
    const float* __restrict__ gamma, const float* __restrict__ beta,
    const int* __restrict__ mask)
{
    const int idx = blockIdx.x*256 + threadIdx.x;
    const int t4 = idx & 127;
    const int c  = (idx >> 7) & 255;
    const int bb = idx >> 15;
    float4 v = ((const float4*)x)[idx];
    const int4 mk = *(const int4*)&mask[bb*NT + t4*4];
    const float mean = stats[c] * (1.f/16384.f);
    const float var  = fmaxf(stats[NC + c]*(1.f/16384.f) - mean*mean, 0.f);
    const float rstd = rsqrtf(var + 1e-5f);
    const float g = gamma[c], be = beta[c];
    v.x = mk.x ? fmaf((v.x - mean)*rstd, g, be) : 0.f;
    v.y = mk.y ? fmaf((v.y - mean)*rstd, g, be) : 0.f;
    v.z = mk.z ? fmaf((v.z - mean)*rstd, g, be) : 0.f;
    v.w = mk.w ? fmaf((v.w - mean)*rstd, g, be) : 0.f;
    ((float4*)x)[idx] = v;
}

extern "C" void kernel_launch(void* const* d_in, const int* in_sizes, int n_in,
                              void* d_out, int out_size, void* d_ws, size_t ws_size,
                              hipStream_t stream)
{
    const float* seq   = (const float*)d_in[0];
    const int*   mask  = (const int*)  d_in[1];
    const float* Wq    = (const float*)d_in[2];
    const float* bq    = (const float*)d_in[3];
    const float* Wk    = (const float*)d_in[4];
    const float* bk    = (const float*)d_in[5];
    const float* Wv    = (const float*)d_in[6];
    const float* bv    = (const float*)d_in[7];
    const float* gamma = (const float*)d_in[8];
    const float* beta  = (const float*)d_in[9];
    float* out = (float*)d_out;

    const size_t perMat = (size_t)NB*NH*NT*ND;   // 4,194,304 elements
    float*  stats = (float*)d_ws;                 // 512 f32
    __bf16* Qh    = (__bf16*)((char*)d_ws + 4096);
    __bf16* Kh    = Qh  + perMat;
    __bf16* VhT   = Kh  + perMat;
    __bf16* seqT  = VhT + perMat;                 // [b][t][c] bf16
    __bf16* Wb    = seqT + perMat;                // [p][co][c] bf16

    prep_seq<<<dim3(NT/64, NB), 256, 0, stream>>>(seq, seqT);
    prep_w<<<dim3(192), 256, 0, stream>>>(Wq, Wk, Wv, Wb, stats);
    qkv_mfma<<<dim3(NT/128, NC/64, NB), 256, 0, stream>>>(
        seqT, Wb, bq, bk, bv, mask, Qh, Kh, VhT);
    attn_mfma<<<dim3(NT/128, NH, NB), 256, 0, stream>>>(
        Qh, Kh, VhT, mask, out, stats);
    bn_apply_kernel<<<dim3((NB*NC*NT/4)/256), 256, 0, stream>>>(
        out, stats, gamma, beta, mask);
}